// Round 7
// baseline (4075.996 us; speedup 1.0000x reference)
//
#include <hip/hip_runtime.h>

// Problem constants
constexpr int B = 64, T = 1024, D = 128, H = 256;
// RNN partition: 16 batch-groups (4 batches each) x 16 blocks (16 units each).
// Weights LDS-stationary: 16 units x 3 gates x (256+128) floats = 72 KB/block.
constexpr int NG = 16;   // batch groups
constexpr int GB = 4;    // batches per group
constexpr int GK = 16;   // blocks per group
constexpr int UO = 16;   // hidden units owned per block

__device__ __forceinline__ float sigmoidf_(float v) {
    return 1.f / (1.f + __expf(-v));
}
__device__ __forceinline__ float tanhf_(float v) {
    float e2 = __expf(2.f * v);
    return 1.f - 2.f / (e2 + 1.f);
}

// ---------------- P1: per-(b,d) scan over t (prefetch-unrolled) ----------------
__global__ __launch_bounds__(64) void prep_scan(
    const float* __restrict__ x, const int* __restrict__ mask,
    const float* __restrict__ ts, const float* __restrict__ it0,
    float* __restrict__ ffill, float* __restrict__ idelta,
    float* __restrict__ mean, float* __restrict__ tdlv)
{
    const int b = blockIdx.x;
    const int d = blockIdx.y * 64 + threadIdx.x;
    float prev_x = 0.f, prev_td = 0.f, osum = 0.f, mcnt = 0.f;
    float prev_ts = it0[b];               // init_time is (1,B) -> flat[b]
    const int baseT = b * T;
    constexpr int U = 16;
    for (int t0 = 0; t0 < T; t0 += U) {
        float xv[U]; int mv[U]; float tsv[U];
        #pragma unroll
        for (int uu = 0; uu < U; ++uu) {
            const int idx = (baseT + t0 + uu) * D + d;
            xv[uu] = x[idx];
            mv[uu] = mask[idx];
        }
        #pragma unroll
        for (int uu = 0; uu < U; ++uu) tsv[uu] = ts[baseT + t0 + uu];
        #pragma unroll
        for (int uu = 0; uu < U; ++uu) {
            const float td = tsv[uu] - prev_ts;
            prev_ts = tsv[uu];
            const int idx = (baseT + t0 + uu) * D + d;
            if (!mv[uu]) { prev_x = xv[uu]; osum += xv[uu]; } else { mcnt += 1.f; }
            prev_td += td;
            ffill[idx]  = prev_x;
            idelta[idx] = prev_td;
            if (!mv[uu]) prev_td = 0.f;
            if (d == 0) tdlv[baseT + t0 + uu] = logf(fminf(fmaxf(td, 0.f), 1000.f));
        }
    }
    mean[b * D + d] = osum / fmaxf(mcnt, 1.f);
}

// ---------------- P2: imputation matvec ----------------
constexpr int ROWS = 64;   // (b,t) rows per block
__global__ __launch_bounds__(256) void fill_kernel(
    const float* __restrict__ x, const int* __restrict__ mask,
    const float* __restrict__ ffill, const float* __restrict__ idelta,
    const float* __restrict__ mean, const float* __restrict__ idw,
    const float* __restrict__ idb, float* __restrict__ xf)
{
    __shared__ float widw[128 * 129];   // padded: conflict-free
    __shared__ float ide[2][128];
    const int tid = threadIdx.x;
    for (int i = tid; i < 128 * 128; i += 256)
        widw[(i >> 7) * 129 + (i & 127)] = idw[i];
    __syncthreads();
    const int p = tid >> 7, d = tid & 127;
    const float bias = idb[d];
    const int row0 = blockIdx.x * ROWS;
    for (int r = 0; r < ROWS; r += 2) {
        const int rowp = row0 + r + p;    // b*T + t
        const int idx = rowp * D + d;
        ide[p][d] = fminf(fmaxf(idelta[idx] - 1.f, 0.f), 1000.f);
        __syncthreads();
        float acc = bias;
        #pragma unroll
        for (int k = 0; k < 128; ++k)
            acc = fmaf(ide[p][k], widw[d * 129 + k], acc);
        float fw = __expf(-fmaxf(acc, 0.f));
        float filled = ffill[idx] * fw + (1.f - fw) * mean[(rowp >> 10) * D + d];
        xf[idx] = mask[idx] ? filled : x[idx];
        __syncthreads();
    }
}

// ---------------- P3: persistent grouped GRU-D recurrence ----------------
// Weights LDS-stationary (loaded once). Fence-free tagged 64-bit LLC exchange
// (tag = step+1 | f32 bits), parity double-buffered hdec, one barrier/step.
// Reduce-scatter over the 16 kc lanes: lane kc ends with item kc = bb*4 + gate
// (0=r,1=z,2=nx,3=nh); lanes kc&3==0 publish batch kc>>2.
__global__ __launch_bounds__(256) void rnn_kernel(
    const float* __restrict__ xf, const float* __restrict__ tdlv,
    const float* __restrict__ w_ih, const float* __restrict__ w_hh,
    const float* __restrict__ b_ih, const float* __restrict__ b_hh,
    const float* __restrict__ hdw, const float* __restrict__ hdb,
    unsigned long long* __restrict__ hx, float* __restrict__ out)
{
    const int tid = threadIdx.x;
    const int g  = blockIdx.x & (NG - 1);   // batch group (members same XCD mod 8)
    const int kb = blockIdx.x >> 4;         // owns units [kb*16, kb*16+16)
    const int u  = tid >> 4;                // 0..15 unit-local
    const int kc = tid & 15;                // 0..15 k-chunk lane
    const int row = kb * UO + u;            // owned hidden unit
    const int b0 = g * GB;                  // first batch of group

    // LDS: weights in thread-chunk-sequential layout (chunk c of thread tid at
    // float offset (c*256+tid)*4) + skew-strided hdec (20-float chunks).
    __shared__ float wlds[18 * 256 * 4];        // 73728 B
    __shared__ float hdecf[2 * GB * 320];       // 10240 B

    // ---- one-time: stage weights into LDS ----
    // chunks 0..11: w_hh gates r,z,n (4 chunks of 4 floats each = 16 k-floats)
    #pragma unroll
    for (int gg = 0; gg < 3; ++gg)
        #pragma unroll
        for (int jc = 0; jc < 4; ++jc) {
            float4 w = *(const float4*)&w_hh[(size_t)(row + gg * H) * H + kc * 16 + jc * 4];
            *(float4*)&wlds[((gg * 4 + jc) * 256 + tid) * 4] = w;
        }
    // chunks 12..17: w_ih gates r,z,n (2 chunks = 8 k-floats)
    #pragma unroll
    for (int gg = 0; gg < 3; ++gg)
        #pragma unroll
        for (int jc = 0; jc < 2; ++jc) {
            float4 w = *(const float4*)&w_ih[(size_t)(row + gg * H) * D + kc * 8 + jc * 4];
            *(float4*)&wlds[((12 + gg * 2 + jc) * 256 + tid) * 4] = w;
        }
    for (int i = tid; i < 2 * GB * 320; i += 256)
        hdecf[i] = 0.f;                     // h0 = 0 (decayed 0 is 0)

    // per-thread constants
    const float hdwk = hdw[tid];            // decay params for staged unit k=tid
    const float hdbk = hdb[tid];
    const float hdwo = hdw[row];            // decay params for owned unit
    const float hdbo = hdb[row];
    const float br  = b_ih[row] + b_hh[row];
    const float bz  = b_ih[H + row] + b_hh[H + row];
    const float bnx = b_ih[2 * H + row];
    const float bnh = b_hh[2 * H + row];
    const bool ownk = ((tid >> 4) == kb);   // staged unit k=tid is block-local

    __syncthreads();

    for (int t = 0; t < T; ++t) {
        const int par = t & 1;

        // ---- (a) probe remote tag words (4 slots, same producer block) ----
        const bool need = (t > 0) && !ownk;
        const unsigned long long* slotp =
            hx + (size_t)((t - 1) & 1) * (B * H) + b0 * H + tid;
        unsigned long long v64[GB];
        if (need) {
            #pragma unroll
            for (int bb = 0; bb < GB; ++bb)
                v64[bb] = __hip_atomic_load(slotp + bb * H,
                                            __ATOMIC_RELAXED, __HIP_MEMORY_SCOPE_AGENT);
        }

        // ---- (b) x loads + tdl loads ----
        float4 xa[GB], xb[GB];
        float tdc[GB], tdn[GB];
        #pragma unroll
        for (int bb = 0; bb < GB; ++bb) {
            const float* xp = xf + (size_t)((b0 + bb) * T + t) * D + kc * 8;
            xa[bb] = *(const float4*)xp;
            xb[bb] = *(const float4*)(xp + 4);
            tdc[bb] = tdlv[(b0 + bb) * T + t];
            tdn[bb] = (t + 1 < T) ? tdlv[(b0 + bb) * T + t + 1] : 0.f;
        }

        // items: v[bb*4 + a], a: 0=r 1=z 2=nx 3=nh
        float v[16];
        #pragma unroll
        for (int i = 0; i < 16; ++i) v[i] = 0.f;

        // ---- (c) gi partials from LDS weights (chunks 12..17) ----
        #pragma unroll
        for (int jc = 0; jc < 2; ++jc)
            #pragma unroll
            for (int gg = 0; gg < 3; ++gg) {
                float4 w4 = *(const float4*)&wlds[((12 + gg * 2 + jc) * 256 + tid) * 4];
                #pragma unroll
                for (int bb = 0; bb < GB; ++bb) {
                    float4 xv = jc ? xb[bb] : xa[bb];
                    float acc = v[bb * 4 + gg];   // gg: 0->r 1->z 2->nx
                    acc = fmaf(w4.x, xv.x, acc);
                    acc = fmaf(w4.y, xv.y, acc);
                    acc = fmaf(w4.z, xv.z, acc);
                    acc = fmaf(w4.w, xv.w, acc);
                    v[bb * 4 + gg] = acc;
                }
            }

        // ---- (d) finish poll + stage decayed remote h into LDS ----
        if (need) {
            for (;;) {
                bool ok = true;
                #pragma unroll
                for (int bb = 0; bb < GB; ++bb)
                    ok = ok && ((unsigned)(v64[bb] >> 32) == (unsigned)t);
                if (ok) break;
                #pragma unroll
                for (int bb = 0; bb < GB; ++bb)
                    v64[bb] = __hip_atomic_load(slotp + bb * H,
                                                __ATOMIC_RELAXED, __HIP_MEMORY_SCOPE_AGENT);
            }
            #pragma unroll
            for (int bb = 0; bb < GB; ++bb) {
                float hv = __uint_as_float((unsigned)v64[bb]);
                float dec = __expf(-fmaxf(tdc[bb] * hdwk + hdbk, 0.f));
                hdecf[(par * GB + bb) * 320 + (tid >> 4) * 20 + (tid & 15)] = hv * dec;
            }
        }
        __syncthreads();

        // ---- (e) gh partials: LDS weights (chunks 0..11) x LDS hdec ----
        #pragma unroll
        for (int jc = 0; jc < 4; ++jc) {
            float4 h4[GB];
            #pragma unroll
            for (int bb = 0; bb < GB; ++bb)
                h4[bb] = *(const float4*)&hdecf[(par * GB + bb) * 320 + kc * 20 + jc * 4];
            #pragma unroll
            for (int gg = 0; gg < 3; ++gg) {
                float4 w4 = *(const float4*)&wlds[((gg * 4 + jc) * 256 + tid) * 4];
                const int a = (gg < 2) ? gg : 3;   // gh n-part -> nh
                #pragma unroll
                for (int bb = 0; bb < GB; ++bb) {
                    float acc = v[bb * 4 + a];
                    acc = fmaf(w4.x, h4[bb].x, acc);
                    acc = fmaf(w4.y, h4[bb].y, acc);
                    acc = fmaf(w4.z, h4[bb].z, acc);
                    acc = fmaf(w4.w, h4[bb].w, acc);
                    v[bb * 4 + a] = acc;
                }
            }
        }

        // ---- (f) reduce-scatter over 16 kc lanes: lane kc ends with item kc ----
        #pragma unroll
        for (int m = 8; m >= 1; m >>= 1) {
            const bool sel = (kc & m);
            #pragma unroll
            for (int j = 0; j < m; ++j) {
                float lo = v[j], hi = v[j + m];
                float keep = sel ? hi : lo;
                float send = sel ? lo : hi;
                v[j] = keep + __shfl_xor(send, m, 64);
            }
        }
        float vfin = v[0];
        float zv  = __shfl_xor(vfin, 1, 64);
        float nxv = __shfl_xor(vfin, 2, 64);
        float nhv = __shfl_xor(vfin, 3, 64);

        // ---- (g) publisher lanes (kc&3==0): batch bbq = kc>>2 ----
        if ((kc & 3) == 0) {
            const int bbq = kc >> 2;
            float r = sigmoidf_(vfin + br);
            float z = sigmoidf_(zv + bz);
            float n = tanhf_(nxv + bnx + r * (nhv + bnh));
            float hd = hdecf[(par * GB + bbq) * 320 + kb * 20 + u];
            float hnew = (1.f - z) * n + z * hd;
            // publish to LLC first (tag = t+1)
            __hip_atomic_store(hx + (size_t)par * (B * H) + (b0 + bbq) * H + row,
                               (((unsigned long long)(unsigned)(t + 1)) << 32) |
                               (unsigned long long)__float_as_uint(hnew),
                               __ATOMIC_RELAXED, __HIP_MEMORY_SCOPE_AGENT);
            // pre-stage own unit's decayed h for t+1 (read only after next barrier)
            if (t + 1 < T) {
                float dec = __expf(-fmaxf(tdn[bbq] * hdwo + hdbo, 0.f));
                hdecf[((par ^ 1) * GB + bbq) * 320 + kb * 20 + u] = hnew * dec;
            }
            out[(size_t)((b0 + bbq) * T + t) * H + row] = hnew;
            if (t == T - 1)
                out[(size_t)B * T * H + (b0 + bbq) * H + row] = hnew;
        }
        // single barrier per step: parity buffering + the collective barrier
        // order all hdec writes before their reads (skew-1 proof as before).
    }
}

extern "C" void kernel_launch(void* const* d_in, const int* in_sizes, int n_in,
                              void* d_out, int out_size, void* d_ws, size_t ws_size,
                              hipStream_t stream) {
    (void)in_sizes; (void)n_in; (void)out_size; (void)ws_size;
    const float* x    = (const float*)d_in[0];
    const int*   mask = (const int*)d_in[1];
    const float* ts   = (const float*)d_in[2];
    const float* it0  = (const float*)d_in[3];
    const float* w_ih = (const float*)d_in[4];
    const float* w_hh = (const float*)d_in[5];
    const float* b_ih = (const float*)d_in[6];
    const float* b_hh = (const float*)d_in[7];
    const float* idw  = (const float*)d_in[8];
    const float* idb  = (const float*)d_in[9];
    const float* hdw  = (const float*)d_in[10];
    const float* hdb  = (const float*)d_in[11];
    float* out = (float*)d_out;

    // Workspace layout (bytes)
    char* ws = (char*)d_ws;
    float* xf   = (float*)(ws);                              // 33554432 B
    float* tdlv = (float*)(ws + 33554432);                   // 262144 B
    float* mean = (float*)(ws + 33816576);                   // 32768 B
    unsigned long long* hx = (unsigned long long*)(ws + 33849344); // 2*B*H u64

    // d_out used as scratch before the RNN overwrites it entirely:
    float* ffill  = out;
    float* idelta = out + (size_t)B * T * D;

    // zero tag words each launch (replay safety)
    hipMemsetAsync(hx, 0, (size_t)(2 * B * H) * 8, stream);

    prep_scan<<<dim3(B, 2), 64, 0, stream>>>(x, mask, ts, it0, ffill, idelta, mean, tdlv);
    fill_kernel<<<(B * T) / ROWS, 256, 0, stream>>>(x, mask, ffill, idelta, mean, idw, idb, xf);
    rnn_kernel<<<NG * GK, 256, 0, stream>>>(xf, tdlv, w_ih, w_hh, b_ih, b_hh, hdw, hdb,
                                            hx, out);
}